// Round 8
// baseline (8324.659 us; speedup 1.0000x reference)
//
#include <hip/hip_runtime.h>
#include <math.h>

// ---------------- problem constants ----------------
#define EPSP 5.0f
#define BNEPS 1e-5f
constexpr int B_  = 64;    // batch
constexpr int T_  = 768;   // timesteps in
constexpr int D_  = 128;   // input feature
constexpr int E_  = 64;    // embedding (conv out channels)
constexpr int H_  = 128;   // hidden
constexpr int FH_ = 512;   // 4*H
constexpr int TC_ = 256;   // conv output steps
constexpr int O_  = 10;    // output classes

// ---------------- workspace layout (floats) ----------------
constexpr size_t EMB_OFF = 0;                                   // B*TC*E   [b][tc][e]
constexpr size_t SUM_OFF = EMB_OFF + (size_t)B_ * TC_ * E_;     // 128  (sum[64], ssq[64])
constexpr size_t SCL_OFF = SUM_OFF + 128;                       // 128  (scale[64], shift[64])
constexpr size_t WT_OFF  = SCL_OFF + 128;                       // 24576: w_ih transposed [gate(i,f,g)][e][j]
constexpr size_t WIH_OFF = WT_OFF + (size_t)FH_ * H_;           // 32768  packed [e4][j][4] (zx_kernel)
constexpr size_t CWT_OFF = WIH_OFF + (size_t)FH_ * E_;          // 24576  [k][d][e]
constexpr size_t ZX_OFF  = CWT_OFF + (size_t)E_ * D_ * 3;       // B*TC*FH [b][t][j]
constexpr size_t WS_FLOATS = ZX_OFF + (size_t)B_ * TC_ * FH_;

typedef __bf16 bf16x8 __attribute__((ext_vector_type(8)));
typedef __bf16 bf16x4 __attribute__((ext_vector_type(4)));
typedef float  floatx4 __attribute__((ext_vector_type(4)));

__device__ inline float fast_rcp(float x) {
#if __has_builtin(__builtin_amdgcn_rcpf)
  return __builtin_amdgcn_rcpf(x);
#else
  return 1.0f / x;
#endif
}
__device__ inline float frsq(float x) {
#if __has_builtin(__builtin_amdgcn_rsqf)
  return __builtin_amdgcn_rsqf(x);
#else
  return rsqrtf(x);
#endif
}
__device__ inline float fexp2(float x) {
#if __has_builtin(__builtin_amdgcn_exp2f)
  return __builtin_amdgcn_exp2f(x);
#else
  return exp2f(x);
#endif
}
__device__ inline float rl(float v, int lane) {
  return __int_as_float(__builtin_amdgcn_readlane(__float_as_int(v), lane));
}
#define LOG2E 1.4426950408889634f
__device__ inline float fsigmoid(float x) {
  return fast_rcp(1.f + fexp2(-LOG2E * x));
}
__device__ inline float ftanh(float x) {
  return 1.f - 2.f * fast_rcp(1.f + fexp2(2.f * LOG2E * x));
}

// ---------------- prep: weight repack + zero BN sums ----------------
__global__ void prep_kernel(const float* __restrict__ conv_w,
                            const float* __restrict__ w_ih,
                            float* __restrict__ ws) {
  int gid = blockIdx.x * blockDim.x + threadIdx.x;
  int nthr = gridDim.x * blockDim.x;
  for (int i = gid; i < 128; i += nthr) ws[SUM_OFF + i] = 0.f;
  // w_ih [512][64] -> packed [16][512][4]  (zx_kernel)
  for (int s = gid; s < FH_ * E_; s += nthr) {
    int j = s >> 6, e = s & 63;
    ws[WIH_OFF + ((size_t)(e >> 2) * FH_ + j) * 4 + (e & 3)] = w_ih[s];
  }
  // w_ih gates i,f,g transposed: Wt[g][e][j] = w_ih[(g*128+j)*64+e]  (scan G-build)
  for (int s = gid; s < 3 * H_ * E_ * 2; s += nthr) {   // 3*64*128 = 24576
    int g = s >> 13; int r = s & 8191; int e = r >> 7; int j = r & 127;
    ws[WT_OFF + s] = w_ih[((size_t)(g * 128 + j)) * 64 + e];
  }
  // conv_w [e][d][k] -> [k][d][e]
  for (int s = gid; s < E_ * D_ * 3; s += nthr) {
    int e = s / 384; int r = s - e * 384; int d = r / 3; int k = r - d * 3;
    ws[CWT_OFF + ((size_t)k * D_ + d) * E_ + e] = conv_w[s];
  }
}

// ---------------- conv + L2-normalize + BN partial sums ----------------
__global__ __launch_bounds__(256) void conv_bn_kernel(const float* __restrict__ inputs,
                                                      const float* __restrict__ conv_b,
                                                      float* __restrict__ ws) {
  __shared__ float xin[48 * 129];
  __shared__ float rnorm[48];
  __shared__ float cwc[3 * 16 * 64];
  __shared__ float bnr1[256], bnr2[256];
  int tid = threadIdx.x;
  int bb = blockIdx.x >> 4, tcg = blockIdx.x & 15;
  const float* inp = inputs + ((size_t)bb * T_ + (size_t)tcg * 48) * D_;
  for (int idx = tid; idx < 48 * 128; idx += 256) {
    int r = idx >> 7, d = idx & 127;
    xin[r * 129 + d] = inp[idx];
  }
  __syncthreads();
  if (tid < 48) {
    float ss = 0.f;
    for (int d = 0; d < 128; ++d) { float v = xin[tid * 129 + d]; ss += v * v; }
    rnorm[tid] = 1.0f / fmaxf(sqrtf(ss), 1e-12f);
  }
  __syncthreads();
  for (int idx = tid; idx < 48 * 128; idx += 256) {
    int r = idx >> 7, d = idx & 127;
    xin[r * 129 + d] *= rnorm[r];
  }
  int e = tid & 63, tg = tid >> 6;
  float cb = conv_b[e];
  float acc[4];
#pragma unroll
  for (int q = 0; q < 4; ++q) acc[q] = cb;
  for (int ch = 0; ch < 8; ++ch) {
    __syncthreads();
    for (int idx = tid; idx < 3072; idx += 256) {
      int k = idx >> 10; int i2 = idx & 1023; int dd = i2 >> 6; int e2 = i2 & 63;
      cwc[idx] = ws[CWT_OFF + ((size_t)k * D_ + ch * 16 + dd) * E_ + e2];
    }
    __syncthreads();
    for (int dd = 0; dd < 16; ++dd) {
      int dcol = ch * 16 + dd;
#pragma unroll
      for (int k = 0; k < 3; ++k) {
        float w = cwc[(k * 16 + dd) * 64 + e];
#pragma unroll
        for (int q = 0; q < 4; ++q) {
          int tcl = tg * 4 + q;
          acc[q] += w * xin[(3 * tcl + k) * 129 + dcol];
        }
      }
    }
  }
  float ps = 0.f, pss = 0.f;
#pragma unroll
  for (int q = 0; q < 4; ++q) {
    int tcl = tg * 4 + q;
    ws[EMB_OFF + ((size_t)bb * TC_ + tcg * 16 + tcl) * E_ + e] = acc[q];
    ps += acc[q]; pss += acc[q] * acc[q];
  }
  bnr1[tg * 64 + e] = ps;
  bnr2[tg * 64 + e] = pss;
  __syncthreads();
  if (tid < 64) {
    float s1 = bnr1[tid] + bnr1[64 + tid] + bnr1[128 + tid] + bnr1[192 + tid];
    float s2 = bnr2[tid] + bnr2[64 + tid] + bnr2[128 + tid] + bnr2[192 + tid];
    atomicAdd(&ws[SUM_OFF + tid], s1);
    atomicAdd(&ws[SUM_OFF + 64 + tid], s2);
  }
}

// ---------------- BN finalize ----------------
__global__ void bn_finalize_kernel(const float* __restrict__ gamma,
                                   const float* __restrict__ beta,
                                   float* __restrict__ ws) {
  int e = threadIdx.x;
  if (e < 64) {
    const float n = (float)(B_ * TC_);
    float mean = ws[SUM_OFF + e] / n;
    float var = ws[SUM_OFF + 64 + e] / n - mean * mean;
    float sc = gamma[e] * rsqrtf(var + BNEPS);
    ws[SCL_OFF + e] = sc;
    ws[SCL_OFF + 64 + e] = beta[e] - mean * sc;
  }
}

// ---------------- z_x = relu(bn(emb)) @ w_ih^T + b_ih + b_hh ----------------
__global__ __launch_bounds__(256) void zx_kernel(const float* __restrict__ b_ih,
                                                 const float* __restrict__ b_hh,
                                                 float* __restrict__ ws) {
  __shared__ __align__(16) float actT[16 * 64];
  int tid = threadIdx.x;
  int bb = blockIdx.x >> 4, tg2 = blockIdx.x & 15;
  for (int idx = tid; idx < 1024; idx += 256) {
    int tl = idx >> 6, e2 = idx & 63;
    float v = ws[EMB_OFF + ((size_t)bb * TC_ + tg2 * 16 + tl) * E_ + e2];
    actT[idx] = fmaxf(v * ws[SCL_OFF + e2] + ws[SCL_OFF + 64 + e2], 0.f);
  }
  __syncthreads();
  int j0 = tid, j1 = tid + 256;
  float acc0[16], acc1[16];
  float bias0 = b_ih[j0] + b_hh[j0];
  float bias1 = b_ih[j1] + b_hh[j1];
#pragma unroll
  for (int tl = 0; tl < 16; ++tl) { acc0[tl] = bias0; acc1[tl] = bias1; }
  const float* wp = ws + WIH_OFF;
  for (int e4 = 0; e4 < 16; ++e4) {
    float4 w0 = *(const float4*)(wp + ((size_t)e4 * FH_ + j0) * 4);
    float4 w1 = *(const float4*)(wp + ((size_t)e4 * FH_ + j1) * 4);
#pragma unroll
    for (int tl = 0; tl < 16; ++tl) {
      float4 a4 = *(const float4*)(actT + tl * 64 + e4 * 4);
      acc0[tl] += w0.x * a4.x + w0.y * a4.y + w0.z * a4.z + w0.w * a4.w;
      acc1[tl] += w1.x * a4.x + w1.y * a4.y + w1.z * a4.z + w1.w * a4.w;
    }
  }
#pragma unroll
  for (int tl = 0; tl < 16; ++tl) {
    size_t base = ZX_OFF + ((size_t)bb * TC_ + tg2 * 16 + tl) * FH_;
    ws[base + j0] = acc0[tl];
    ws[base + j1] = acc1[tl];
  }
}

// ---------------- the sequential ProxLSTM scan: 1 block/batch, 1024 threads ----------------
// w_hh lives permanently in VGPRs as bf16 hi/lo MFMA A-fragments (64 VGPRs/thread).
// __launch_bounds__(1024,4): 4 waves/EU (exactly one resident block) -> 128-VGPR cap,
// which the 80-reg persistent fragment set needs. R6's default allocated 64 -> massive
// HBM spill (FETCH 635 MB). This is the single variable changed vs R6.
__global__ __launch_bounds__(1024, 4) void scan_kernel(const float* __restrict__ w_hh,
                                                       const float* __restrict__ lin_w,
                                                       const float* __restrict__ lin_b,
                                                       const float* __restrict__ ws,
                                                       float* __restrict__ out) {
  __shared__ __align__(16) __bf16 GtHi[80 * 136], GtLo[80 * 136];  // rows 0-63 = G^T[e][h], 64 = s
  __shared__ __align__(16) __bf16 BxHi[16 * 72], BxLo[16 * 72];    // row 0 = x (others garbage, unused)
  __shared__ __align__(16) __bf16 hbH[128], hbL[128];              // h split bf16
  __shared__ float M_s[64 * 65];
  __shared__ float Lp_s[16 * 64];
  __shared__ __align__(16) float z0_s[512], z1_s[512], zx_s[512];
  __shared__ __align__(16) float s_s[128], o_s[128], c_s[128], h_s[128];
  __shared__ float y_s[64];

  const int tid = threadIdx.x;
  const int bb = blockIdx.x;
  const int lane = tid & 63;
  const int wv = tid >> 6;            // 0..15
  const int m = lane & 15, q = lane >> 4;
  const int hg = tid >> 5;            // 0..31  (G-build: 4 h-rows)
  const int ep = tid & 31;            // 0..31  (G-build: 2 e-cols)
  const int h0 = hg * 4, e0 = ep * 2;

  // ---- persistent w_hh MFMA A-fragments (bf16 hi/lo), 64 VGPRs ----
  bf16x8 WH[2][4], WL[2][4];
#pragma unroll
  for (int rti = 0; rti < 2; ++rti) {
    int R = (wv * 2 + rti) * 16 + m;
#pragma unroll
    for (int kt = 0; kt < 4; ++kt) {
      const float* p = w_hh + (size_t)R * 128 + kt * 32 + q * 8;
      float4 a = *(const float4*)p;
      float4 b2 = *(const float4*)(p + 4);
      float v0[8] = {a.x, a.y, a.z, a.w, b2.x, b2.y, b2.z, b2.w};
#pragma unroll
      for (int j = 0; j < 8; ++j) {
        __bf16 hi = (__bf16)v0[j];
        WH[rti][kt][j] = hi;
        WL[rti][kt][j] = (__bf16)(v0[j] - (float)hi);
      }
    }
  }

  if (tid < 128) {
    c_s[tid] = 0.f; h_s[tid] = 0.f;
    hbH[tid] = (__bf16)0.f; hbL[tid] = (__bf16)0.f;
  }
  const float* zxp = ws + ZX_OFF + (size_t)bb * TC_ * FH_;
  const float* wt  = ws + WT_OFF;
  float zx = (tid < 512) ? zxp[tid] : 0.f;
  float dinv = 1.f;          // wave-0: 1/L[lane][lane]
  bf16x8 EH[2], EL[2];       // E-phase A-fragments (prefetched during pan-3)
  __syncthreads();

  for (int t = 0; t < TC_; ++t) {
    float4 tv[6];
    // ---- A: z = W_hh.h via MFMA (16/wave); lanes m=0/1 hold the two h-halves ----
    {
      bf16x8 Bf[4];
#pragma unroll
      for (int kt = 0; kt < 4; ++kt) {
        bf16x8 hh = *(const bf16x8*)(hbH + kt * 32 + q * 8);
        bf16x8 hl = *(const bf16x8*)(hbL + kt * 32 + q * 8);
        Bf[kt] = (m == 1) ? hl : hh;
      }
      floatx4 CA0 = {0,0,0,0}, CA1 = {0,0,0,0}, CB0 = {0,0,0,0}, CB1 = {0,0,0,0};
#pragma unroll
      for (int kt = 0; kt < 4; ++kt) {
        CA0 = __builtin_amdgcn_mfma_f32_16x16x32_bf16(WH[0][kt], Bf[kt], CA0, 0, 0, 0);
        CA1 = __builtin_amdgcn_mfma_f32_16x16x32_bf16(WH[1][kt], Bf[kt], CA1, 0, 0, 0);
        CB0 = __builtin_amdgcn_mfma_f32_16x16x32_bf16(WL[0][kt], Bf[kt], CB0, 0, 0, 0);
        CB1 = __builtin_amdgcn_mfma_f32_16x16x32_bf16(WL[1][kt], Bf[kt], CB1, 0, 0, 0);
      }
      // issue G-build weight stream (drains at this barrier, hidden behind z writes)
#pragma unroll
      for (int g = 0; g < 3; ++g)
#pragma unroll
        for (int e = 0; e < 2; ++e)
          tv[g * 2 + e] = *(const float4*)(wt + (size_t)g * 8192 + (size_t)(e0 + e) * 128 + h0);
      if (tid < 512) zx_s[tid] = zx;
      if (m == 0) {
#pragma unroll
        for (int r = 0; r < 4; ++r) {
          z0_s[(wv * 2 + 0) * 16 + q * 4 + r] = CA0[r] + CB0[r];
          z0_s[(wv * 2 + 1) * 16 + q * 4 + r] = CA1[r] + CB1[r];
        }
      } else if (m == 1) {
#pragma unroll
        for (int r = 0; r < 4; ++r) {
          z1_s[(wv * 2 + 0) * 16 + q * 4 + r] = CA0[r] + CB0[r];
          z1_s[(wv * 2 + 1) * 16 + q * 4 + r] = CA1[r] + CB1[r];
        }
      }
    }
    __syncthreads();
    // ---- G-build with fused gates (each thread: 4 h-rows x 2 e-cols) ----
    {
      float4 vi, vf, vg, vo;
      {
        float4 a0 = *(const float4*)(z0_s + h0), b0 = *(const float4*)(z1_s + h0), x0 = *(const float4*)(zx_s + h0);
        vi.x = a0.x + b0.x + x0.x; vi.y = a0.y + b0.y + x0.y; vi.z = a0.z + b0.z + x0.z; vi.w = a0.w + b0.w + x0.w;
        float4 a1 = *(const float4*)(z0_s + 128 + h0), b1 = *(const float4*)(z1_s + 128 + h0), x1 = *(const float4*)(zx_s + 128 + h0);
        vf.x = a1.x + b1.x + x1.x; vf.y = a1.y + b1.y + x1.y; vf.z = a1.z + b1.z + x1.z; vf.w = a1.w + b1.w + x1.w;
        float4 a2 = *(const float4*)(z0_s + 256 + h0), b2 = *(const float4*)(z1_s + 256 + h0), x2 = *(const float4*)(zx_s + 256 + h0);
        vg.x = a2.x + b2.x + x2.x; vg.y = a2.y + b2.y + x2.y; vg.z = a2.z + b2.z + x2.z; vg.w = a2.w + b2.w + x2.w;
        float4 a3 = *(const float4*)(z0_s + 384 + h0), b3 = *(const float4*)(z1_s + 384 + h0), x3 = *(const float4*)(zx_s + 384 + h0);
        vo.x = a3.x + b3.x + x3.x; vo.y = a3.y + b3.y + x3.y; vo.z = a3.z + b3.z + x3.z; vo.w = a3.w + b3.w + x3.w;
      }
      float4 cc = *(const float4*)(c_s + h0);
      float ziA[4] = {vi.x, vi.y, vi.z, vi.w};
      float zfA[4] = {vf.x, vf.y, vf.z, vf.w};
      float zgA[4] = {vg.x, vg.y, vg.z, vg.w};
      float zoA[4] = {vo.x, vo.y, vo.z, vo.w};
      float cA[4]  = {cc.x, cc.y, cc.z, cc.w};
      float sv[4], ov[4], A1[4], A2[4], A3[4];
#pragma unroll
      for (int r = 0; r < 4; ++r) {
        float ig = fsigmoid(ziA[r]);
        float fg = fsigmoid(zfA[r]);
        float gg = ftanh(zgA[r]);
        sv[r] = fg * cA[r] + ig * gg;
        ov[r] = fsigmoid(zoA[r]);
        A1[r] = ig * (1.f - ig) * gg;
        A2[r] = fg * (1.f - fg) * cA[r];
        A3[r] = ig * (1.f - gg * gg);
      }
      if (ep == 0) {
        *(float4*)(s_s + h0) = (float4){sv[0], sv[1], sv[2], sv[3]};
        *(float4*)(o_s + h0) = (float4){ov[0], ov[1], ov[2], ov[3]};
        bf16x4 sh, sl;
#pragma unroll
        for (int r = 0; r < 4; ++r) {
          __bf16 hi = (__bf16)sv[r];
          sh[r] = hi; sl[r] = (__bf16)(sv[r] - (float)hi);
        }
        *(bf16x4*)(GtHi + 64 * 136 + h0) = sh;
        *(bf16x4*)(GtLo + 64 * 136 + h0) = sl;
      }
      const float* tvf = (const float*)tv;   // tvf[(g*2+e)*4 + r]
#pragma unroll
      for (int e = 0; e < 2; ++e) {
        bf16x4 gh, gl;
#pragma unroll
        for (int r = 0; r < 4; ++r) {
          float gv = A1[r] * tvf[e * 4 + r] + A2[r] * tvf[8 + e * 4 + r] + A3[r] * tvf[16 + e * 4 + r];
          __bf16 hi = (__bf16)gv;
          gh[r] = hi; gl[r] = (__bf16)(gv - (float)hi);
        }
        *(bf16x4*)(GtHi + (e0 + e) * 136 + h0) = gh;
        *(bf16x4*)(GtLo + (e0 + e) * 136 + h0) = gl;
      }
      if (tid < 512 && t + 1 < TC_) zx = zxp[(size_t)(t + 1) * FH_ + tid];
    }
    __syncthreads();
    // ---- Gram via MFMA: 16 units (rt,ci<4) + 4 y-units (ci=4 on waves 12-15) ----
    {
      int rt = wv & 3, ci0 = wv >> 2;
      bf16x8 Ah[4], Al[4];
#pragma unroll
      for (int kt = 0; kt < 4; ++kt) {
        Ah[kt] = *(const bf16x8*)(GtHi + (rt * 16 + m) * 136 + kt * 32 + q * 8);
        Al[kt] = *(const bf16x8*)(GtLo + (rt * 16 + m) * 136 + kt * 32 + q * 8);
      }
#pragma unroll
      for (int un = 0; un < 2; ++un) {
        int ci = (un == 0) ? ci0 : 4;
        if (un == 1 && wv < 12) break;
        floatx4 C = {0,0,0,0};
#pragma unroll
        for (int p = 0; p < 3; ++p) {
          const __bf16* Bb = (p == 1) ? GtLo : GtHi;
#pragma unroll
          for (int kt = 0; kt < 4; ++kt) {
            bf16x8 Bf = *(const bf16x8*)(Bb + (ci * 16 + m) * 136 + kt * 32 + q * 8);
            bf16x8 Af = (p < 2) ? Ah[kt] : Al[kt];
            C = __builtin_amdgcn_mfma_f32_16x16x32_bf16(Af, Bf, C, 0, 0, 0);
          }
        }
#pragma unroll
        for (int reg = 0; reg < 4; ++reg) {
          int grow = rt * 16 + q * 4 + reg;
          if (ci < 4) {
            int gcol = ci * 16 + m;
            M_s[grow * 65 + gcol] = EPSP * C[reg] + ((grow == gcol) ? 1.f : 0.f);
          } else if (m == 0) {
            y_s[grow] = C[reg];
          }
        }
      }
    }
    __syncthreads();
    // ---- Cholesky: factor (wave 0) + trailing (16 waves); E-prefetch during pan 3 ----
#pragma unroll 1
    for (int pan = 0; pan < 4; ++pan) {
      int j0 = pan * 16;
      if (wv == 0) {
        float p[16];
#pragma unroll
        for (int jj = 0; jj < 16; ++jj) p[jj] = M_s[lane * 65 + j0 + jj];
#pragma unroll
        for (int jj = 0; jj < 16; ++jj) {
          float d  = rl(p[jj], j0 + jj);
          float rs = frsq(d);
          p[jj] *= rs;                         // diag lane: d*rs = sqrt(d)
          dinv = (lane == j0 + jj) ? rs : dinv;
#pragma unroll
          for (int kk = jj + 1; kk < 16; ++kk) {
            float l = rl(p[jj], j0 + kk);
            p[kk] -= p[jj] * l;
          }
        }
#pragma unroll
        for (int jj = 0; jj < 16; ++jj) {
          M_s[lane * 65 + j0 + jj] = p[jj];
          Lp_s[jj * 64 + lane] = p[jj];
        }
        if (pan == 3) {
          float r = y_s[lane];
          // forward: L y' = y
#pragma unroll 16
          for (int i = 0; i < 64; ++i) {
            float Lri = M_s[lane * 65 + i];
            float vv  = rl(r, i) * rl(dinv, i);
            float upd = r - Lri * vv;
            r = (lane == i) ? vv : ((lane > i) ? upd : r);
          }
          // backward: L^T x = y'
#pragma unroll 16
          for (int i = 63; i >= 0; --i) {
            float Lil = M_s[i * 65 + lane];
            float vv  = rl(r, i) * rl(dinv, i);
            float upd = r - Lil * vv;
            r = (lane == i) ? vv : ((lane < i) ? upd : r);
          }
          __bf16 xh = (__bf16)r;
          BxHi[lane] = xh;
          BxLo[lane] = (__bf16)(r - (float)xh);
        }
      } else if (pan == 3 && wv >= 8) {
        // prefetch E A-fragments (G rows rt_e*16.., transposed from Gt) while wave 0 solves
        int rte = wv - 8;
#pragma unroll
        for (int kt = 0; kt < 2; ++kt) {
#pragma unroll
          for (int j = 0; j < 8; ++j) {
            int e = kt * 32 + q * 8 + j;
            EH[kt][j] = GtHi[e * 136 + rte * 16 + m];
            EL[kt][j] = GtLo[e * 136 + rte * 16 + m];
          }
        }
      }
      __syncthreads();
      if (pan < 3) {
        float Lrow[16];
#pragma unroll
        for (int jj = 0; jj < 16; ++jj) Lrow[jj] = Lp_s[jj * 64 + lane];
        for (int k = j0 + 16 + wv; k < 64; k += 16) {
          float acc = M_s[lane * 65 + k];
#pragma unroll
          for (int jj = 0; jj < 16; ++jj) acc -= Lrow[jj] * Lp_s[jj * 64 + k];
          M_s[lane * 65 + k] = acc;
        }
        __syncthreads();
      }
    }
    // ---- E: u = G x via MFMA (waves 8-15, prefetched frags); c,h update ----
    if (wv >= 8) {
      int rte = wv - 8;
      floatx4 C = {0,0,0,0};
#pragma unroll
      for (int p = 0; p < 3; ++p) {
        const __bf16* Bb = (p == 1) ? BxLo : BxHi;
#pragma unroll
        for (int kt = 0; kt < 2; ++kt) {
          bf16x8 Bf = *(const bf16x8*)(Bb + m * 72 + kt * 32 + q * 8);
          bf16x8 Af = (p < 2) ? EH[kt] : EL[kt];
          C = __builtin_amdgcn_mfma_f32_16x16x32_bf16(Af, Bf, C, 0, 0, 0);
        }
      }
      if (m == 0) {
#pragma unroll
        for (int reg = 0; reg < 4; ++reg) {
          int grow = rte * 16 + q * 4 + reg;
          float cn = s_s[grow] - EPSP * C[reg];
          float hn = o_s[grow] * ftanh(cn);
          c_s[grow] = cn;
          h_s[grow] = hn;
          __bf16 hi = (__bf16)hn;
          hbH[grow] = hi;
          hbL[grow] = (__bf16)(hn - (float)hi);
        }
      }
    }
    __syncthreads();
  }
  // ---- head ----
  if (tid < O_) {
    float acc = lin_b[tid];
    for (int hh2 = 0; hh2 < 128; ++hh2) acc += h_s[hh2] * lin_w[tid * 128 + hh2];
    out[(size_t)bb * O_ + tid] = acc;
  }
}

// ---------------- launch ----------------
extern "C" void kernel_launch(void* const* d_in, const int* in_sizes, int n_in,
                              void* d_out, int out_size, void* d_ws, size_t ws_size,
                              hipStream_t stream) {
  (void)in_sizes; (void)n_in; (void)out_size;
  const float* inputs  = (const float*)d_in[0];
  const float* conv_w  = (const float*)d_in[2];
  const float* conv_b  = (const float*)d_in[3];
  const float* gamma   = (const float*)d_in[4];
  const float* beta    = (const float*)d_in[5];
  const float* w_ih    = (const float*)d_in[6];
  const float* w_hh    = (const float*)d_in[7];
  const float* b_ih    = (const float*)d_in[8];
  const float* b_hh    = (const float*)d_in[9];
  const float* lin_w   = (const float*)d_in[10];
  const float* lin_b   = (const float*)d_in[11];
  float* out = (float*)d_out;
  float* ws  = (float*)d_ws;

  if (ws_size < WS_FLOATS * sizeof(float)) return;

  hipLaunchKernelGGL(prep_kernel, dim3(192), dim3(256), 0, stream, conv_w, w_ih, ws);
  hipLaunchKernelGGL(conv_bn_kernel, dim3(1024), dim3(256), 0, stream, inputs, conv_b, ws);
  hipLaunchKernelGGL(bn_finalize_kernel, dim3(1), dim3(64), 0, stream, gamma, beta, ws);
  hipLaunchKernelGGL(zx_kernel, dim3(1024), dim3(256), 0, stream, b_ih, b_hh, ws);
  hipLaunchKernelGGL(scan_kernel, dim3(64), dim3(1024), 0, stream, w_hh, lin_w, lin_b, ws, out);
}

// Round 9
// 8287.221 us; speedup vs baseline: 1.0045x; 1.0045x over previous
//
#include <hip/hip_runtime.h>
#include <math.h>

// ---------------- problem constants ----------------
#define EPSP 5.0f
#define BNEPS 1e-5f
constexpr int B_  = 64;    // batch
constexpr int T_  = 768;   // timesteps in
constexpr int D_  = 128;   // input feature
constexpr int E_  = 64;    // embedding (conv out channels)
constexpr int H_  = 128;   // hidden
constexpr int FH_ = 512;   // 4*H
constexpr int TC_ = 256;   // conv output steps
constexpr int O_  = 10;    // output classes

// ---------------- workspace layout (floats) ----------------
constexpr size_t EMB_OFF = 0;                                   // B*TC*E   [b][tc][e]
constexpr size_t SUM_OFF = EMB_OFF + (size_t)B_ * TC_ * E_;     // 128  (sum[64], ssq[64])
constexpr size_t SCL_OFF = SUM_OFF + 128;                       // 128  (scale[64], shift[64])
constexpr size_t WT_OFF  = SCL_OFF + 128;                       // 24576: w_ih transposed [gate(i,f,g)][e][j]
constexpr size_t WIH_OFF = WT_OFF + (size_t)FH_ * H_;           // 32768  packed [e4][j][4] (zx_kernel)
constexpr size_t CWT_OFF = WIH_OFF + (size_t)FH_ * E_;          // 24576  [k][d][e]
constexpr size_t ZX_OFF  = CWT_OFF + (size_t)E_ * D_ * 3;       // B*TC*FH [b][t][j]
constexpr size_t WS_FLOATS = ZX_OFF + (size_t)B_ * TC_ * FH_;

typedef __bf16 bf16x8 __attribute__((ext_vector_type(8)));
typedef __bf16 bf16x4 __attribute__((ext_vector_type(4)));
typedef float  floatx4 __attribute__((ext_vector_type(4)));

__device__ inline float fast_rcp(float x) {
#if __has_builtin(__builtin_amdgcn_rcpf)
  return __builtin_amdgcn_rcpf(x);
#else
  return 1.0f / x;
#endif
}
__device__ inline float frsq(float x) {
#if __has_builtin(__builtin_amdgcn_rsqf)
  return __builtin_amdgcn_rsqf(x);
#else
  return rsqrtf(x);
#endif
}
__device__ inline float fexp2(float x) {
#if __has_builtin(__builtin_amdgcn_exp2f)
  return __builtin_amdgcn_exp2f(x);
#else
  return exp2f(x);
#endif
}
__device__ inline float rl(float v, int lane) {
  return __int_as_float(__builtin_amdgcn_readlane(__float_as_int(v), lane));
}
#define LOG2E 1.4426950408889634f
__device__ inline float fsigmoid(float x) {
  return fast_rcp(1.f + fexp2(-LOG2E * x));
}
__device__ inline float ftanh(float x) {
  return 1.f - 2.f * fast_rcp(1.f + fexp2(2.f * LOG2E * x));
}

// ---------------- prep: weight repack + zero BN sums ----------------
__global__ void prep_kernel(const float* __restrict__ conv_w,
                            const float* __restrict__ w_ih,
                            float* __restrict__ ws) {
  int gid = blockIdx.x * blockDim.x + threadIdx.x;
  int nthr = gridDim.x * blockDim.x;
  for (int i = gid; i < 128; i += nthr) ws[SUM_OFF + i] = 0.f;
  // w_ih [512][64] -> packed [16][512][4]  (zx_kernel)
  for (int s = gid; s < FH_ * E_; s += nthr) {
    int j = s >> 6, e = s & 63;
    ws[WIH_OFF + ((size_t)(e >> 2) * FH_ + j) * 4 + (e & 3)] = w_ih[s];
  }
  // w_ih gates i,f,g transposed: Wt[g][e][j] = w_ih[(g*128+j)*64+e]  (scan G-build)
  for (int s = gid; s < 3 * H_ * E_ * 2; s += nthr) {   // 3*64*128 = 24576
    int g = s >> 13; int r = s & 8191; int e = r >> 7; int j = r & 127;
    ws[WT_OFF + s] = w_ih[((size_t)(g * 128 + j)) * 64 + e];
  }
  // conv_w [e][d][k] -> [k][d][e]
  for (int s = gid; s < E_ * D_ * 3; s += nthr) {
    int e = s / 384; int r = s - e * 384; int d = r / 3; int k = r - d * 3;
    ws[CWT_OFF + ((size_t)k * D_ + d) * E_ + e] = conv_w[s];
  }
}

// ---------------- conv + L2-normalize + BN partial sums ----------------
__global__ __launch_bounds__(256) void conv_bn_kernel(const float* __restrict__ inputs,
                                                      const float* __restrict__ conv_b,
                                                      float* __restrict__ ws) {
  __shared__ float xin[48 * 129];
  __shared__ float rnorm[48];
  __shared__ float cwc[3 * 16 * 64];
  __shared__ float bnr1[256], bnr2[256];
  int tid = threadIdx.x;
  int bb = blockIdx.x >> 4, tcg = blockIdx.x & 15;
  const float* inp = inputs + ((size_t)bb * T_ + (size_t)tcg * 48) * D_;
  for (int idx = tid; idx < 48 * 128; idx += 256) {
    int r = idx >> 7, d = idx & 127;
    xin[r * 129 + d] = inp[idx];
  }
  __syncthreads();
  if (tid < 48) {
    float ss = 0.f;
    for (int d = 0; d < 128; ++d) { float v = xin[tid * 129 + d]; ss += v * v; }
    rnorm[tid] = 1.0f / fmaxf(sqrtf(ss), 1e-12f);
  }
  __syncthreads();
  for (int idx = tid; idx < 48 * 128; idx += 256) {
    int r = idx >> 7, d = idx & 127;
    xin[r * 129 + d] *= rnorm[r];
  }
  int e = tid & 63, tg = tid >> 6;
  float cb = conv_b[e];
  float acc[4];
#pragma unroll
  for (int q = 0; q < 4; ++q) acc[q] = cb;
  for (int ch = 0; ch < 8; ++ch) {
    __syncthreads();
    for (int idx = tid; idx < 3072; idx += 256) {
      int k = idx >> 10; int i2 = idx & 1023; int dd = i2 >> 6; int e2 = i2 & 63;
      cwc[idx] = ws[CWT_OFF + ((size_t)k * D_ + ch * 16 + dd) * E_ + e2];
    }
    __syncthreads();
    for (int dd = 0; dd < 16; ++dd) {
      int dcol = ch * 16 + dd;
#pragma unroll
      for (int k = 0; k < 3; ++k) {
        float w = cwc[(k * 16 + dd) * 64 + e];
#pragma unroll
        for (int q = 0; q < 4; ++q) {
          int tcl = tg * 4 + q;
          acc[q] += w * xin[(3 * tcl + k) * 129 + dcol];
        }
      }
    }
  }
  float ps = 0.f, pss = 0.f;
#pragma unroll
  for (int q = 0; q < 4; ++q) {
    int tcl = tg * 4 + q;
    ws[EMB_OFF + ((size_t)bb * TC_ + tcg * 16 + tcl) * E_ + e] = acc[q];
    ps += acc[q]; pss += acc[q] * acc[q];
  }
  bnr1[tg * 64 + e] = ps;
  bnr2[tg * 64 + e] = pss;
  __syncthreads();
  if (tid < 64) {
    float s1 = bnr1[tid] + bnr1[64 + tid] + bnr1[128 + tid] + bnr1[192 + tid];
    float s2 = bnr2[tid] + bnr2[64 + tid] + bnr2[128 + tid] + bnr2[192 + tid];
    atomicAdd(&ws[SUM_OFF + tid], s1);
    atomicAdd(&ws[SUM_OFF + 64 + tid], s2);
  }
}

// ---------------- BN finalize ----------------
__global__ void bn_finalize_kernel(const float* __restrict__ gamma,
                                   const float* __restrict__ beta,
                                   float* __restrict__ ws) {
  int e = threadIdx.x;
  if (e < 64) {
    const float n = (float)(B_ * TC_);
    float mean = ws[SUM_OFF + e] / n;
    float var = ws[SUM_OFF + 64 + e] / n - mean * mean;
    float sc = gamma[e] * rsqrtf(var + BNEPS);
    ws[SCL_OFF + e] = sc;
    ws[SCL_OFF + 64 + e] = beta[e] - mean * sc;
  }
}

// ---------------- z_x = relu(bn(emb)) @ w_ih^T + b_ih + b_hh ----------------
__global__ __launch_bounds__(256) void zx_kernel(const float* __restrict__ b_ih,
                                                 const float* __restrict__ b_hh,
                                                 float* __restrict__ ws) {
  __shared__ __align__(16) float actT[16 * 64];
  int tid = threadIdx.x;
  int bb = blockIdx.x >> 4, tg2 = blockIdx.x & 15;
  for (int idx = tid; idx < 1024; idx += 256) {
    int tl = idx >> 6, e2 = idx & 63;
    float v = ws[EMB_OFF + ((size_t)bb * TC_ + tg2 * 16 + tl) * E_ + e2];
    actT[idx] = fmaxf(v * ws[SCL_OFF + e2] + ws[SCL_OFF + 64 + e2], 0.f);
  }
  __syncthreads();
  int j0 = tid, j1 = tid + 256;
  float acc0[16], acc1[16];
  float bias0 = b_ih[j0] + b_hh[j0];
  float bias1 = b_ih[j1] + b_hh[j1];
#pragma unroll
  for (int tl = 0; tl < 16; ++tl) { acc0[tl] = bias0; acc1[tl] = bias1; }
  const float* wp = ws + WIH_OFF;
  for (int e4 = 0; e4 < 16; ++e4) {
    float4 w0 = *(const float4*)(wp + ((size_t)e4 * FH_ + j0) * 4);
    float4 w1 = *(const float4*)(wp + ((size_t)e4 * FH_ + j1) * 4);
#pragma unroll
    for (int tl = 0; tl < 16; ++tl) {
      float4 a4 = *(const float4*)(actT + tl * 64 + e4 * 4);
      acc0[tl] += w0.x * a4.x + w0.y * a4.y + w0.z * a4.z + w0.w * a4.w;
      acc1[tl] += w1.x * a4.x + w1.y * a4.y + w1.z * a4.z + w1.w * a4.w;
    }
  }
#pragma unroll
  for (int tl = 0; tl < 16; ++tl) {
    size_t base = ZX_OFF + ((size_t)bb * TC_ + tg2 * 16 + tl) * FH_;
    ws[base + j0] = acc0[tl];
    ws[base + j1] = acc1[tl];
  }
}

// ---------------- the sequential ProxLSTM scan: 1 block/batch, 1024 threads ----------------
// w_hh lives permanently in VGPRs as bf16 hi/lo MFMA A-fragments (64 VGPRs/thread).
// amdgpu_waves_per_eu(4,4): forces the register allocator's occupancy TARGET to
// exactly 4 waves/EU (= one resident 16-wave block) -> 128-VGPR budget. Evidence:
// __launch_bounds__ min-waves alone was ignored (R3: (512,1)->128 regs unchanged;
// R7: (1024,4)->64 regs unchanged; both = the heuristic's 2-blocks/CU target).
__global__ __launch_bounds__(1024)
__attribute__((amdgpu_waves_per_eu(4, 4)))
void scan_kernel(const float* __restrict__ w_hh,
                 const float* __restrict__ lin_w,
                 const float* __restrict__ lin_b,
                 const float* __restrict__ ws,
                 float* __restrict__ out) {
  __shared__ __align__(16) __bf16 GtHi[80 * 136], GtLo[80 * 136];  // rows 0-63 = G^T[e][h], 64 = s
  __shared__ __align__(16) __bf16 BxHi[16 * 72], BxLo[16 * 72];    // row 0 = x (others garbage, unused)
  __shared__ __align__(16) __bf16 hbH[128], hbL[128];              // h split bf16
  __shared__ float M_s[64 * 65];
  __shared__ float Lp_s[16 * 64];
  __shared__ __align__(16) float z0_s[512], z1_s[512], zx_s[512];
  __shared__ __align__(16) float s_s[128], o_s[128], c_s[128], h_s[128];
  __shared__ float y_s[64];

  const int tid = threadIdx.x;
  const int bb = blockIdx.x;
  const int lane = tid & 63;
  const int wv = tid >> 6;            // 0..15
  const int m = lane & 15, q = lane >> 4;
  const int hg = tid >> 5;            // 0..31  (G-build: 4 h-rows)
  const int ep = tid & 31;            // 0..31  (G-build: 2 e-cols)
  const int h0 = hg * 4, e0 = ep * 2;

  // ---- persistent w_hh MFMA A-fragments (bf16 hi/lo), 64 VGPRs ----
  bf16x8 WH[2][4], WL[2][4];
#pragma unroll
  for (int rti = 0; rti < 2; ++rti) {
    int R = (wv * 2 + rti) * 16 + m;
#pragma unroll
    for (int kt = 0; kt < 4; ++kt) {
      const float* p = w_hh + (size_t)R * 128 + kt * 32 + q * 8;
      float4 a = *(const float4*)p;
      float4 b2 = *(const float4*)(p + 4);
      float v0[8] = {a.x, a.y, a.z, a.w, b2.x, b2.y, b2.z, b2.w};
#pragma unroll
      for (int j = 0; j < 8; ++j) {
        __bf16 hi = (__bf16)v0[j];
        WH[rti][kt][j] = hi;
        WL[rti][kt][j] = (__bf16)(v0[j] - (float)hi);
      }
    }
  }

  if (tid < 128) {
    c_s[tid] = 0.f; h_s[tid] = 0.f;
    hbH[tid] = (__bf16)0.f; hbL[tid] = (__bf16)0.f;
  }
  const float* zxp = ws + ZX_OFF + (size_t)bb * TC_ * FH_;
  const float* wt  = ws + WT_OFF;
  float zx = (tid < 512) ? zxp[tid] : 0.f;
  float dinv = 1.f;          // wave-0: 1/L[lane][lane]
  bf16x8 EH[2], EL[2];       // E-phase A-fragments (prefetched during pan-3)
  __syncthreads();

  for (int t = 0; t < TC_; ++t) {
    float4 tv[6];
    // ---- A: z = W_hh.h via MFMA (16/wave); lanes m=0/1 hold the two h-halves ----
    {
      bf16x8 Bf[4];
#pragma unroll
      for (int kt = 0; kt < 4; ++kt) {
        bf16x8 hh = *(const bf16x8*)(hbH + kt * 32 + q * 8);
        bf16x8 hl = *(const bf16x8*)(hbL + kt * 32 + q * 8);
        Bf[kt] = (m == 1) ? hl : hh;
      }
      floatx4 CA0 = {0,0,0,0}, CA1 = {0,0,0,0}, CB0 = {0,0,0,0}, CB1 = {0,0,0,0};
#pragma unroll
      for (int kt = 0; kt < 4; ++kt) {
        CA0 = __builtin_amdgcn_mfma_f32_16x16x32_bf16(WH[0][kt], Bf[kt], CA0, 0, 0, 0);
        CA1 = __builtin_amdgcn_mfma_f32_16x16x32_bf16(WH[1][kt], Bf[kt], CA1, 0, 0, 0);
        CB0 = __builtin_amdgcn_mfma_f32_16x16x32_bf16(WL[0][kt], Bf[kt], CB0, 0, 0, 0);
        CB1 = __builtin_amdgcn_mfma_f32_16x16x32_bf16(WL[1][kt], Bf[kt], CB1, 0, 0, 0);
      }
      // issue G-build weight stream (drains at this barrier, hidden behind z writes)
#pragma unroll
      for (int g = 0; g < 3; ++g)
#pragma unroll
        for (int e = 0; e < 2; ++e)
          tv[g * 2 + e] = *(const float4*)(wt + (size_t)g * 8192 + (size_t)(e0 + e) * 128 + h0);
      if (tid < 512) zx_s[tid] = zx;
      if (m == 0) {
#pragma unroll
        for (int r = 0; r < 4; ++r) {
          z0_s[(wv * 2 + 0) * 16 + q * 4 + r] = CA0[r] + CB0[r];
          z0_s[(wv * 2 + 1) * 16 + q * 4 + r] = CA1[r] + CB1[r];
        }
      } else if (m == 1) {
#pragma unroll
        for (int r = 0; r < 4; ++r) {
          z1_s[(wv * 2 + 0) * 16 + q * 4 + r] = CA0[r] + CB0[r];
          z1_s[(wv * 2 + 1) * 16 + q * 4 + r] = CA1[r] + CB1[r];
        }
      }
    }
    __syncthreads();
    // ---- G-build with fused gates (each thread: 4 h-rows x 2 e-cols) ----
    {
      float4 vi, vf, vg, vo;
      {
        float4 a0 = *(const float4*)(z0_s + h0), b0 = *(const float4*)(z1_s + h0), x0 = *(const float4*)(zx_s + h0);
        vi.x = a0.x + b0.x + x0.x; vi.y = a0.y + b0.y + x0.y; vi.z = a0.z + b0.z + x0.z; vi.w = a0.w + b0.w + x0.w;
        float4 a1 = *(const float4*)(z0_s + 128 + h0), b1 = *(const float4*)(z1_s + 128 + h0), x1 = *(const float4*)(zx_s + 128 + h0);
        vf.x = a1.x + b1.x + x1.x; vf.y = a1.y + b1.y + x1.y; vf.z = a1.z + b1.z + x1.z; vf.w = a1.w + b1.w + x1.w;
        float4 a2 = *(const float4*)(z0_s + 256 + h0), b2 = *(const float4*)(z1_s + 256 + h0), x2 = *(const float4*)(zx_s + 256 + h0);
        vg.x = a2.x + b2.x + x2.x; vg.y = a2.y + b2.y + x2.y; vg.z = a2.z + b2.z + x2.z; vg.w = a2.w + b2.w + x2.w;
        float4 a3 = *(const float4*)(z0_s + 384 + h0), b3 = *(const float4*)(z1_s + 384 + h0), x3 = *(const float4*)(zx_s + 384 + h0);
        vo.x = a3.x + b3.x + x3.x; vo.y = a3.y + b3.y + x3.y; vo.z = a3.z + b3.z + x3.z; vo.w = a3.w + b3.w + x3.w;
      }
      float4 cc = *(const float4*)(c_s + h0);
      float ziA[4] = {vi.x, vi.y, vi.z, vi.w};
      float zfA[4] = {vf.x, vf.y, vf.z, vf.w};
      float zgA[4] = {vg.x, vg.y, vg.z, vg.w};
      float zoA[4] = {vo.x, vo.y, vo.z, vo.w};
      float cA[4]  = {cc.x, cc.y, cc.z, cc.w};
      float sv[4], ov[4], A1[4], A2[4], A3[4];
#pragma unroll
      for (int r = 0; r < 4; ++r) {
        float ig = fsigmoid(ziA[r]);
        float fg = fsigmoid(zfA[r]);
        float gg = ftanh(zgA[r]);
        sv[r] = fg * cA[r] + ig * gg;
        ov[r] = fsigmoid(zoA[r]);
        A1[r] = ig * (1.f - ig) * gg;
        A2[r] = fg * (1.f - fg) * cA[r];
        A3[r] = ig * (1.f - gg * gg);
      }
      if (ep == 0) {
        *(float4*)(s_s + h0) = (float4){sv[0], sv[1], sv[2], sv[3]};
        *(float4*)(o_s + h0) = (float4){ov[0], ov[1], ov[2], ov[3]};
        bf16x4 sh, sl;
#pragma unroll
        for (int r = 0; r < 4; ++r) {
          __bf16 hi = (__bf16)sv[r];
          sh[r] = hi; sl[r] = (__bf16)(sv[r] - (float)hi);
        }
        *(bf16x4*)(GtHi + 64 * 136 + h0) = sh;
        *(bf16x4*)(GtLo + 64 * 136 + h0) = sl;
      }
      const float* tvf = (const float*)tv;   // tvf[(g*2+e)*4 + r]
#pragma unroll
      for (int e = 0; e < 2; ++e) {
        bf16x4 gh, gl;
#pragma unroll
        for (int r = 0; r < 4; ++r) {
          float gv = A1[r] * tvf[e * 4 + r] + A2[r] * tvf[8 + e * 4 + r] + A3[r] * tvf[16 + e * 4 + r];
          __bf16 hi = (__bf16)gv;
          gh[r] = hi; gl[r] = (__bf16)(gv - (float)hi);
        }
        *(bf16x4*)(GtHi + (e0 + e) * 136 + h0) = gh;
        *(bf16x4*)(GtLo + (e0 + e) * 136 + h0) = gl;
      }
      if (tid < 512 && t + 1 < TC_) zx = zxp[(size_t)(t + 1) * FH_ + tid];
    }
    __syncthreads();
    // ---- Gram via MFMA: 16 units (rt,ci<4) + 4 y-units (ci=4 on waves 12-15) ----
    {
      int rt = wv & 3, ci0 = wv >> 2;
      bf16x8 Ah[4], Al[4];
#pragma unroll
      for (int kt = 0; kt < 4; ++kt) {
        Ah[kt] = *(const bf16x8*)(GtHi + (rt * 16 + m) * 136 + kt * 32 + q * 8);
        Al[kt] = *(const bf16x8*)(GtLo + (rt * 16 + m) * 136 + kt * 32 + q * 8);
      }
#pragma unroll
      for (int un = 0; un < 2; ++un) {
        int ci = (un == 0) ? ci0 : 4;
        if (un == 1 && wv < 12) break;
        floatx4 C = {0,0,0,0};
#pragma unroll
        for (int p = 0; p < 3; ++p) {
          const __bf16* Bb = (p == 1) ? GtLo : GtHi;
#pragma unroll
          for (int kt = 0; kt < 4; ++kt) {
            bf16x8 Bf = *(const bf16x8*)(Bb + (ci * 16 + m) * 136 + kt * 32 + q * 8);
            bf16x8 Af = (p < 2) ? Ah[kt] : Al[kt];
            C = __builtin_amdgcn_mfma_f32_16x16x32_bf16(Af, Bf, C, 0, 0, 0);
          }
        }
#pragma unroll
        for (int reg = 0; reg < 4; ++reg) {
          int grow = rt * 16 + q * 4 + reg;
          if (ci < 4) {
            int gcol = ci * 16 + m;
            M_s[grow * 65 + gcol] = EPSP * C[reg] + ((grow == gcol) ? 1.f : 0.f);
          } else if (m == 0) {
            y_s[grow] = C[reg];
          }
        }
      }
    }
    __syncthreads();
    // ---- Cholesky: factor (wave 0) + trailing (16 waves); E-prefetch during pan 3 ----
#pragma unroll 1
    for (int pan = 0; pan < 4; ++pan) {
      int j0 = pan * 16;
      if (wv == 0) {
        float p[16];
#pragma unroll
        for (int jj = 0; jj < 16; ++jj) p[jj] = M_s[lane * 65 + j0 + jj];
#pragma unroll
        for (int jj = 0; jj < 16; ++jj) {
          float d  = rl(p[jj], j0 + jj);
          float rs = frsq(d);
          p[jj] *= rs;                         // diag lane: d*rs = sqrt(d)
          dinv = (lane == j0 + jj) ? rs : dinv;
#pragma unroll
          for (int kk = jj + 1; kk < 16; ++kk) {
            float l = rl(p[jj], j0 + kk);
            p[kk] -= p[jj] * l;
          }
        }
#pragma unroll
        for (int jj = 0; jj < 16; ++jj) {
          M_s[lane * 65 + j0 + jj] = p[jj];
          Lp_s[jj * 64 + lane] = p[jj];
        }
        if (pan == 3) {
          float r = y_s[lane];
          // forward: L y' = y
#pragma unroll 16
          for (int i = 0; i < 64; ++i) {
            float Lri = M_s[lane * 65 + i];
            float vv  = rl(r, i) * rl(dinv, i);
            float upd = r - Lri * vv;
            r = (lane == i) ? vv : ((lane > i) ? upd : r);
          }
          // backward: L^T x = y'
#pragma unroll 16
          for (int i = 63; i >= 0; --i) {
            float Lil = M_s[i * 65 + lane];
            float vv  = rl(r, i) * rl(dinv, i);
            float upd = r - Lil * vv;
            r = (lane == i) ? vv : ((lane < i) ? upd : r);
          }
          __bf16 xh = (__bf16)r;
          BxHi[lane] = xh;
          BxLo[lane] = (__bf16)(r - (float)xh);
        }
      } else if (pan == 3 && wv >= 8) {
        // prefetch E A-fragments (G rows rt_e*16.., transposed from Gt) while wave 0 solves
        int rte = wv - 8;
#pragma unroll
        for (int kt = 0; kt < 2; ++kt) {
#pragma unroll
          for (int j = 0; j < 8; ++j) {
            int e = kt * 32 + q * 8 + j;
            EH[kt][j] = GtHi[e * 136 + rte * 16 + m];
            EL[kt][j] = GtLo[e * 136 + rte * 16 + m];
          }
        }
      }
      __syncthreads();
      if (pan < 3) {
        float Lrow[16];
#pragma unroll
        for (int jj = 0; jj < 16; ++jj) Lrow[jj] = Lp_s[jj * 64 + lane];
        for (int k = j0 + 16 + wv; k < 64; k += 16) {
          float acc = M_s[lane * 65 + k];
#pragma unroll
          for (int jj = 0; jj < 16; ++jj) acc -= Lrow[jj] * Lp_s[jj * 64 + k];
          M_s[lane * 65 + k] = acc;
        }
        __syncthreads();
      }
    }
    // ---- E: u = G x via MFMA (waves 8-15, prefetched frags); c,h update ----
    if (wv >= 8) {
      int rte = wv - 8;
      floatx4 C = {0,0,0,0};
#pragma unroll
      for (int p = 0; p < 3; ++p) {
        const __bf16* Bb = (p == 1) ? BxLo : BxHi;
#pragma unroll
        for (int kt = 0; kt < 2; ++kt) {
          bf16x8 Bf = *(const bf16x8*)(Bb + m * 72 + kt * 32 + q * 8);
          bf16x8 Af = (p < 2) ? EH[kt] : EL[kt];
          C = __builtin_amdgcn_mfma_f32_16x16x32_bf16(Af, Bf, C, 0, 0, 0);
        }
      }
      if (m == 0) {
#pragma unroll
        for (int reg = 0; reg < 4; ++reg) {
          int grow = rte * 16 + q * 4 + reg;
          float cn = s_s[grow] - EPSP * C[reg];
          float hn = o_s[grow] * ftanh(cn);
          c_s[grow] = cn;
          h_s[grow] = hn;
          __bf16 hi = (__bf16)hn;
          hbH[grow] = hi;
          hbL[grow] = (__bf16)(hn - (float)hi);
        }
      }
    }
    __syncthreads();
  }
  // ---- head ----
  if (tid < O_) {
    float acc = lin_b[tid];
    for (int hh2 = 0; hh2 < 128; ++hh2) acc += h_s[hh2] * lin_w[tid * 128 + hh2];
    out[(size_t)bb * O_ + tid] = acc;
  }
}

// ---------------- launch ----------------
extern "C" void kernel_launch(void* const* d_in, const int* in_sizes, int n_in,
                              void* d_out, int out_size, void* d_ws, size_t ws_size,
                              hipStream_t stream) {
  (void)in_sizes; (void)n_in; (void)out_size;
  const float* inputs  = (const float*)d_in[0];
  const float* conv_w  = (const float*)d_in[2];
  const float* conv_b  = (const float*)d_in[3];
  const float* gamma   = (const float*)d_in[4];
  const float* beta    = (const float*)d_in[5];
  const float* w_ih    = (const float*)d_in[6];
  const float* w_hh    = (const float*)d_in[7];
  const float* b_ih    = (const float*)d_in[8];
  const float* b_hh    = (const float*)d_in[9];
  const float* lin_w   = (const float*)d_in[10];
  const float* lin_b   = (const float*)d_in[11];
  float* out = (float*)d_out;
  float* ws  = (float*)d_ws;

  if (ws_size < WS_FLOATS * sizeof(float)) return;

  hipLaunchKernelGGL(prep_kernel, dim3(192), dim3(256), 0, stream, conv_w, w_ih, ws);
  hipLaunchKernelGGL(conv_bn_kernel, dim3(1024), dim3(256), 0, stream, inputs, conv_b, ws);
  hipLaunchKernelGGL(bn_finalize_kernel, dim3(1), dim3(64), 0, stream, gamma, beta, ws);
  hipLaunchKernelGGL(zx_kernel, dim3(1024), dim3(256), 0, stream, b_ih, b_hh, ws);
  hipLaunchKernelGGL(scan_kernel, dim3(64), dim3(1024), 0, stream, w_hh, lin_w, lin_b, ws, out);
}

// Round 10
// 6147.580 us; speedup vs baseline: 1.3541x; 1.3480x over previous
//
#include <hip/hip_runtime.h>
#include <math.h>

// ---------------- problem constants ----------------
#define EPSP 5.0f
#define BNEPS 1e-5f
constexpr int B_  = 64;    // batch
constexpr int T_  = 768;   // timesteps in
constexpr int D_  = 128;   // input feature
constexpr int E_  = 64;    // embedding (conv out channels)
constexpr int H_  = 128;   // hidden
constexpr int FH_ = 512;   // 4*H
constexpr int TC_ = 256;   // conv output steps
constexpr int O_  = 10;    // output classes

// ---------------- workspace layout (floats) ----------------
constexpr size_t EMB_OFF   = 0;                                  // B*TC*E
constexpr size_t SUM_OFF   = EMB_OFF + (size_t)B_ * TC_ * E_;    // 128
constexpr size_t SCL_OFF   = SUM_OFF + 128;                      // 128
constexpr size_t CWT_OFF   = SCL_OFF + 128;                      // 24576 [k][d][e]
constexpr size_t WHIF_OFF  = CWT_OFF + (size_t)E_ * D_ * 3;      // 32768: w_hh bf16-hi MFMA frags, per-thread
constexpr size_t WLO8F_OFF = WHIF_OFF + 32768;                   // 16384: w_hh fp8-lo (x2^14) frags, per-thread
constexpr size_t WTHI_OFF  = WLO8F_OFF + 16384;                  // 12288: w_ih bf16-hi [g][e][j]
constexpr size_t WTLO8_OFF = WTHI_OFF + 12288;                   // 6144:  w_ih fp8-lo (x2^14) [g][e][j]
constexpr size_t ZX_OFF    = WTLO8_OFF + 6144;                   // B*TC*FH
constexpr size_t WS_FLOATS = ZX_OFF + (size_t)B_ * TC_ * FH_;    // 9,529,600 < proven 9,560,320 capacity

typedef __bf16 bf16x8 __attribute__((ext_vector_type(8)));
typedef float  floatx4 __attribute__((ext_vector_type(4)));

__device__ inline float fast_rcp(float x) { return __builtin_amdgcn_rcpf(x); }
__device__ inline float frsq(float x) { return __builtin_amdgcn_rsqf(x); }
__device__ inline float fexp2(float x) { return __builtin_amdgcn_exp2f(x); }
__device__ inline float rl(float v, int lane) {
  return __int_as_float(__builtin_amdgcn_readlane(__float_as_int(v), lane));
}
#define LOG2E 1.4426950408889634f
__device__ inline float fsigmoid(float x) { return fast_rcp(1.f + fexp2(-LOG2E * x)); }
__device__ inline float ftanh(float x) { return 1.f - 2.f * fast_rcp(1.f + fexp2(2.f * LOG2E * x)); }

// fp8 e4m3fn encode (truncating, flush-to-zero below 2^-6) / decode. Values pre-scaled to normal range.
__device__ inline unsigned char enc8(float v) {
  unsigned b = __float_as_uint(v);
  unsigned s = b >> 31;
  int e = (int)((b >> 23) & 0xFF) - 127;
  if (e < -6) return 0;
  unsigned m3 = (b >> 20) & 7;
  return (unsigned char)((s << 7) | ((unsigned)(e + 7) << 3) | m3);
}
__device__ inline float dec8(unsigned c) {
  unsigned e = (c >> 3) & 0xF;
  if (e == 0) return 0.f;
  unsigned f = ((c & 0x80u) << 24) | ((e + 120u) << 23) | ((c & 7u) << 20);
  return __uint_as_float(f);
}
#define S14 6.103515625e-05f        // 2^-14
#define S18 3.814697265625e-06f     // 2^-18

// ---------------- prep: weight repack (frags + LDS images) ----------------
__global__ void prep_kernel(const float* __restrict__ conv_w,
                            const float* __restrict__ w_ih,
                            const float* __restrict__ w_hh,
                            float* __restrict__ ws) {
  int gid = blockIdx.x * blockDim.x + threadIdx.x;
  int nthr = gridDim.x * blockDim.x;
  for (int i = gid; i < 128; i += nthr) ws[SUM_OFF + i] = 0.f;
  // w_hh -> per-scan-thread MFMA fragments: thread st (0..511), frag f=(rti,kt), byte j
  __bf16* whiF = (__bf16*)(ws + WHIF_OFF);
  unsigned char* wlo8F = (unsigned char*)(ws + WLO8F_OFF);
  for (int s = gid; s < 512 * 128; s += nthr) {
    int st = s >> 7, r2 = s & 127, f = r2 >> 3, j = r2 & 7;
    int wv = st >> 6, lane = st & 63, m = lane & 15, q = lane >> 4;
    int rti = f >> 2, kt = f & 3;
    int R = wv * 64 + rti * 16 + m;
    int k = kt * 32 + q * 8 + j;
    float w = w_hh[(size_t)R * 128 + k];
    __bf16 hi = (__bf16)w;
    whiF[s] = hi;
    wlo8F[s] = enc8((w - (float)hi) * 16384.f);
  }
  // w_ih transposed images [g][e][j]: bf16-hi + fp8-lo
  __bf16* wthi = (__bf16*)(ws + WTHI_OFF);
  unsigned char* wtlo = (unsigned char*)(ws + WTLO8_OFF);
  for (int s = gid; s < 3 * 64 * 128; s += nthr) {
    int g = s >> 13; int r = s & 8191; int e = r >> 7; int j = r & 127;
    float w = w_ih[((size_t)(g * 128 + j)) * 64 + e];
    __bf16 hi = (__bf16)w;
    wthi[s] = hi;
    wtlo[s] = enc8((w - (float)hi) * 16384.f);
  }
  // conv_w [e][d][k] -> [k][d][e]
  for (int s = gid; s < E_ * D_ * 3; s += nthr) {
    int e = s / 384; int r = s - e * 384; int d = r / 3; int k = r - d * 3;
    ws[CWT_OFF + ((size_t)k * D_ + d) * E_ + e] = conv_w[s];
  }
}

// ---------------- conv + L2-normalize + BN partial sums ----------------
__global__ __launch_bounds__(256) void conv_bn_kernel(const float* __restrict__ inputs,
                                                      const float* __restrict__ conv_b,
                                                      float* __restrict__ ws) {
  __shared__ float xin[48 * 129];
  __shared__ float rnorm[48];
  __shared__ float cwc[3 * 16 * 64];
  __shared__ float bnr1[256], bnr2[256];
  int tid = threadIdx.x;
  int bb = blockIdx.x >> 4, tcg = blockIdx.x & 15;
  const float* inp = inputs + ((size_t)bb * T_ + (size_t)tcg * 48) * D_;
  for (int idx = tid; idx < 48 * 128; idx += 256) {
    int r = idx >> 7, d = idx & 127;
    xin[r * 129 + d] = inp[idx];
  }
  __syncthreads();
  if (tid < 48) {
    float ss = 0.f;
    for (int d = 0; d < 128; ++d) { float v = xin[tid * 129 + d]; ss += v * v; }
    rnorm[tid] = 1.0f / fmaxf(sqrtf(ss), 1e-12f);
  }
  __syncthreads();
  for (int idx = tid; idx < 48 * 128; idx += 256) {
    int r = idx >> 7, d = idx & 127;
    xin[r * 129 + d] *= rnorm[r];
  }
  int e = tid & 63, tg = tid >> 6;
  float cb = conv_b[e];
  float acc[4];
#pragma unroll
  for (int q = 0; q < 4; ++q) acc[q] = cb;
  for (int ch = 0; ch < 8; ++ch) {
    __syncthreads();
    for (int idx = tid; idx < 3072; idx += 256) {
      int k = idx >> 10; int i2 = idx & 1023; int dd = i2 >> 6; int e2 = i2 & 63;
      cwc[idx] = ws[CWT_OFF + ((size_t)k * D_ + ch * 16 + dd) * E_ + e2];
    }
    __syncthreads();
    for (int dd = 0; dd < 16; ++dd) {
      int dcol = ch * 16 + dd;
#pragma unroll
      for (int k = 0; k < 3; ++k) {
        float w = cwc[(k * 16 + dd) * 64 + e];
#pragma unroll
        for (int q = 0; q < 4; ++q) {
          int tcl = tg * 4 + q;
          acc[q] += w * xin[(3 * tcl + k) * 129 + dcol];
        }
      }
    }
  }
  float ps = 0.f, pss = 0.f;
#pragma unroll
  for (int q = 0; q < 4; ++q) {
    int tcl = tg * 4 + q;
    ws[EMB_OFF + ((size_t)bb * TC_ + tcg * 16 + tcl) * E_ + e] = acc[q];
    ps += acc[q]; pss += acc[q] * acc[q];
  }
  bnr1[tg * 64 + e] = ps;
  bnr2[tg * 64 + e] = pss;
  __syncthreads();
  if (tid < 64) {
    float s1 = bnr1[tid] + bnr1[64 + tid] + bnr1[128 + tid] + bnr1[192 + tid];
    float s2 = bnr2[tid] + bnr2[64 + tid] + bnr2[128 + tid] + bnr2[192 + tid];
    atomicAdd(&ws[SUM_OFF + tid], s1);
    atomicAdd(&ws[SUM_OFF + 64 + tid], s2);
  }
}

// ---------------- BN finalize ----------------
__global__ void bn_finalize_kernel(const float* __restrict__ gamma,
                                   const float* __restrict__ beta,
                                   float* __restrict__ ws) {
  int e = threadIdx.x;
  if (e < 64) {
    const float n = (float)(B_ * TC_);
    float mean = ws[SUM_OFF + e] / n;
    float var = ws[SUM_OFF + 64 + e] / n - mean * mean;
    float sc = gamma[e] * rsqrtf(var + BNEPS);
    ws[SCL_OFF + e] = sc;
    ws[SCL_OFF + 64 + e] = beta[e] - mean * sc;
  }
}

// ---------------- z_x = relu(bn(emb)) @ w_ih^T + b_ih + b_hh ----------------
// reads w_ih rows directly (row-major [512][64], contiguous float4s)
__global__ __launch_bounds__(256) void zx_kernel(const float* __restrict__ w_ih,
                                                 const float* __restrict__ b_ih,
                                                 const float* __restrict__ b_hh,
                                                 float* __restrict__ ws) {
  __shared__ __align__(16) float actT[16 * 64];
  int tid = threadIdx.x;
  int bb = blockIdx.x >> 4, tg2 = blockIdx.x & 15;
  for (int idx = tid; idx < 1024; idx += 256) {
    int tl = idx >> 6, e2 = idx & 63;
    float v = ws[EMB_OFF + ((size_t)bb * TC_ + tg2 * 16 + tl) * E_ + e2];
    actT[idx] = fmaxf(v * ws[SCL_OFF + e2] + ws[SCL_OFF + 64 + e2], 0.f);
  }
  __syncthreads();
  int j0 = tid, j1 = tid + 256;
  float acc0[16], acc1[16];
  float bias0 = b_ih[j0] + b_hh[j0];
  float bias1 = b_ih[j1] + b_hh[j1];
#pragma unroll
  for (int tl = 0; tl < 16; ++tl) { acc0[tl] = bias0; acc1[tl] = bias1; }
  for (int e4 = 0; e4 < 16; ++e4) {
    float4 w0 = *(const float4*)(w_ih + (size_t)j0 * 64 + e4 * 4);
    float4 w1 = *(const float4*)(w_ih + (size_t)j1 * 64 + e4 * 4);
#pragma unroll
    for (int tl = 0; tl < 16; ++tl) {
      float4 a4 = *(const float4*)(actT + tl * 64 + e4 * 4);
      acc0[tl] += w0.x * a4.x + w0.y * a4.y + w0.z * a4.z + w0.w * a4.w;
      acc1[tl] += w1.x * a4.x + w1.y * a4.y + w1.z * a4.z + w1.w * a4.w;
    }
  }
#pragma unroll
  for (int tl = 0; tl < 16; ++tl) {
    size_t base = ZX_OFF + ((size_t)bb * TC_ + tg2 * 16 + tl) * FH_;
    ws[base + j0] = acc0[tl];
    ws[base + j1] = acc1[tl];
  }
}

// ---------------- Gram tile helper (proven R4 code) ----------------
template <int NCT>
__device__ inline void gram_do(int rt, int ct0, int lane,
                               const __bf16* GtHi, const __bf16* GtLo,
                               float* M_s, float* y_s) {
  int m = lane & 15, q = lane >> 4;
  floatx4 C[NCT];
#pragma unroll
  for (int ci = 0; ci < NCT; ++ci) C[ci] = (floatx4){0.f, 0.f, 0.f, 0.f};
#pragma unroll
  for (int p = 0; p < 3; ++p) {
    const __bf16* Aa = (p < 2) ? GtHi : GtLo;
    const __bf16* Ba = (p == 1) ? GtLo : GtHi;
    bf16x8 Af[4];
#pragma unroll
    for (int kt = 0; kt < 4; ++kt)
      Af[kt] = *(const bf16x8*)(Aa + (rt * 16 + m) * 136 + kt * 32 + q * 8);
#pragma unroll
    for (int ci = 0; ci < NCT; ++ci) {
#pragma unroll
      for (int kt = 0; kt < 4; ++kt) {
        bf16x8 Bf = *(const bf16x8*)(Ba + ((ct0 + ci) * 16 + m) * 136 + kt * 32 + q * 8);
        C[ci] = __builtin_amdgcn_mfma_f32_16x16x32_bf16(Af[kt], Bf, C[ci], 0, 0, 0);
      }
    }
  }
#pragma unroll
  for (int ci = 0; ci < NCT; ++ci) {
    int ct = ct0 + ci;
#pragma unroll
    for (int reg = 0; reg < 4; ++reg) {
      int grow = rt * 16 + q * 4 + reg;
      if (ct < 4) {
        int gcol = ct * 16 + m;
        M_s[grow * 65 + gcol] = EPSP * C[ci][reg] + ((grow == gcol) ? 1.f : 0.f);
      } else if (m == 0) {
        y_s[grow] = C[ci][reg];
      }
    }
  }
}

#define LD8(dst, base) { float4 _a = *(const float4*)(base); float4 _b = *(const float4*)((base) + 4); \
  dst[0]=_a.x; dst[1]=_a.y; dst[2]=_a.z; dst[3]=_a.w; dst[4]=_b.x; dst[5]=_b.y; dst[6]=_b.z; dst[7]=_b.w; }

union U4L { uint4 u; long l[2]; };

// ---------------- scan: 1 block/batch, 512 threads (reliable 128-VGPR budget) ----------------
// z = W_hh.h via MFMA: bf16-hi frags persistent (64 regs), fp8-lo frags streamed (L2, transient).
// w_ih lives in LDS (bf16-hi + fp8-lo), Gram/E via bf16 hi/lo MFMA, Cholesky per R4.
__global__ __launch_bounds__(512) void scan_kernel(const float* __restrict__ lin_w,
                                                   const float* __restrict__ lin_b,
                                                   const float* __restrict__ ws,
                                                   float* __restrict__ out) {
  __shared__ __align__(16) __bf16 WtHiL[3 * 64 * 128];            // 49152 B
  __shared__ __align__(8)  unsigned char WtLo8L[3 * 64 * 128];    // 24576 B
  __shared__ __align__(16) __bf16 GtHi[80 * 136], GtLo[80 * 136]; // rows 0-63 G^T[e][h], 64 = s, 65-79 = 0
  __shared__ __align__(16) __bf16 BxHi[16 * 72], BxLo[16 * 72];   // row 0 = x, rows 1-15 = 0
  __shared__ __align__(16) __bf16 hbH[128], hbL[128];             // h split bf16
  __shared__ __align__(8)  unsigned char hb8[128];                // h fp8 (x16)
  __shared__ float M_s[64 * 65];
  __shared__ float Lp_s[16 * 64];
  __shared__ __align__(16) float z0_s[512], zx_s[512];
  __shared__ __align__(16) float s_s[128], o_s[128], c_s[128], h_s[128];
  __shared__ float y_s[64];

  const int tid = threadIdx.x;
  const int bb = blockIdx.x;
  const int lane = tid & 63;
  const int wv = tid >> 6;          // 0..7
  const int m = lane & 15, q = lane >> 4;
  const int hg = tid >> 5;          // 0..15 (G-build: 8 rows)
  const int ep = tid & 31;          // 0..31 (G-build: 2 cols)
  const int h0 = hg * 8, e0 = ep * 2;

  // ---- persistent: w_hh bf16-hi MFMA frags (16 x bf16x8 = 64 VGPRs) ----
  bf16x8 WH[4][4];
  {
    const uint4* whip = (const uint4*)(ws + WHIF_OFF) + (size_t)tid * 16;
#pragma unroll
    for (int rti = 0; rti < 4; ++rti)
#pragma unroll
      for (int kt = 0; kt < 4; ++kt) {
        uint4 t4 = whip[rti * 4 + kt];
        WH[rti][kt] = __builtin_bit_cast(bf16x8, t4);
      }
  }
  // ---- load w_ih images into LDS ----
  {
    const unsigned* src = (const unsigned*)(ws + WTHI_OFF);
    unsigned* dst = (unsigned*)WtHiL;
    for (int i = tid; i < 12288; i += 512) dst[i] = src[i];
    const unsigned* src2 = (const unsigned*)(ws + WTLO8_OFF);
    unsigned* dst2 = (unsigned*)WtLo8L;
    for (int i = tid; i < 6144; i += 512) dst2[i] = src2[i];
  }
  // ---- zero-init ----
  for (int i = tid; i < 15 * 136; i += 512) { GtHi[65 * 136 + i] = (__bf16)0.f; GtLo[65 * 136 + i] = (__bf16)0.f; }
  for (int i = tid; i < 15 * 72; i += 512) { BxHi[72 + i] = (__bf16)0.f; BxLo[72 + i] = (__bf16)0.f; }
  if (tid < 128) {
    c_s[tid] = 0.f; h_s[tid] = 0.f;
    hbH[tid] = (__bf16)0.f; hbL[tid] = (__bf16)0.f; hb8[tid] = 0;
  }
  const float* zxp = ws + ZX_OFF + (size_t)bb * TC_ * FH_;
  const uint4* w8p = (const uint4*)(ws + WLO8F_OFF) + (size_t)tid * 8;   // 128 B/thread fp8-lo frags
  float dinv = 1.f;
  bf16x8 ZB;
#pragma unroll
  for (int j = 0; j < 8; ++j) ZB[j] = (__bf16)0.f;
  __syncthreads();

  for (int t = 0; t < TC_; ++t) {
    // ---- A: z = W_hh.h via MFMA (hi x (hh,hl) + fp8 lo x h8) ----
    {
      float zxv = zxp[(size_t)t * FH_ + tid];   // issue early, consumed at end of phase
      long B8[4];
#pragma unroll
      for (int kt = 0; kt < 4; ++kt)
        B8[kt] = (m == 0) ? *(const long*)(hb8 + kt * 32 + q * 8) : 0L;
      floatx4 C[4];
      // fp8-lo correction: frags streamed from L2 (transient regs)
#pragma unroll
      for (int h2 = 0; h2 < 2; ++h2) {
        U4L wa[4];
#pragma unroll
        for (int i = 0; i < 4; ++i) wa[i].u = w8p[h2 * 4 + i];
        floatx4 C8a = {0,0,0,0}, C8b = {0,0,0,0};
#pragma unroll
        for (int kt = 0; kt < 4; ++kt) {
          long A0 = wa[(0 * 4 + kt) >> 1].l[kt & 1];
          long A1 = wa[(1 * 4 + kt) >> 1].l[kt & 1];
          C8a = __builtin_amdgcn_mfma_f32_16x16x32_fp8_fp8(A0, B8[kt], C8a, 0, 0, 0);
          C8b = __builtin_amdgcn_mfma_f32_16x16x32_fp8_fp8(A1, B8[kt], C8b, 0, 0, 0);
        }
        C[h2 * 2 + 0] = C8a * S18;
        C[h2 * 2 + 1] = C8b * S18;
      }
      // bf16-hi x (hh + hl)
#pragma unroll
      for (int p = 0; p < 2; ++p) {
        const __bf16* hb = p ? hbL : hbH;
#pragma unroll
        for (int kt = 0; kt < 4; ++kt) {
          bf16x8 Bf = (m == 0) ? *(const bf16x8*)(hb + kt * 32 + q * 8) : ZB;
#pragma unroll
          for (int rti = 0; rti < 4; ++rti)
            C[rti] = __builtin_amdgcn_mfma_f32_16x16x32_bf16(WH[rti][kt], Bf, C[rti], 0, 0, 0);
        }
      }
      if (m == 0) {
#pragma unroll
        for (int rti = 0; rti < 4; ++rti)
#pragma unroll
          for (int r = 0; r < 4; ++r)
            z0_s[wv * 64 + rti * 16 + q * 4 + r] = C[rti][r];
      }
      zx_s[tid] = zxv;
    }
    __syncthreads();
    // ---- B: gates (redundant x32) + G build from LDS w_ih ----
    {
      float zA[8], xA[8], zi[8], zf[8], zg[8], zo[8], cc[8];
      LD8(zA, z0_s + h0) LD8(xA, zx_s + h0)
#pragma unroll
      for (int r = 0; r < 8; ++r) zi[r] = zA[r] + xA[r];
      LD8(zA, z0_s + 128 + h0) LD8(xA, zx_s + 128 + h0)
#pragma unroll
      for (int r = 0; r < 8; ++r) zf[r] = zA[r] + xA[r];
      LD8(zA, z0_s + 256 + h0) LD8(xA, zx_s + 256 + h0)
#pragma unroll
      for (int r = 0; r < 8; ++r) zg[r] = zA[r] + xA[r];
      LD8(zA, z0_s + 384 + h0) LD8(xA, zx_s + 384 + h0)
#pragma unroll
      for (int r = 0; r < 8; ++r) zo[r] = zA[r] + xA[r];
      LD8(cc, c_s + h0)
      float a1[8], a2[8], a3[8], sv[8], ov[8];
#pragma unroll
      for (int r = 0; r < 8; ++r) {
        float ig = fsigmoid(zi[r]);
        float fg = fsigmoid(zf[r]);
        float gg = ftanh(zg[r]);
        sv[r] = fg * cc[r] + ig * gg;
        ov[r] = fsigmoid(zo[r]);
        a1[r] = ig * (1.f - ig) * gg;
        a2[r] = fg * (1.f - fg) * cc[r];
        a3[r] = ig * (1.f - gg * gg);
      }
      if (ep == 0) {
        *(float4*)(s_s + h0)     = (float4){sv[0], sv[1], sv[2], sv[3]};
        *(float4*)(s_s + h0 + 4) = (float4){sv[4], sv[5], sv[6], sv[7]};
        *(float4*)(o_s + h0)     = (float4){ov[0], ov[1], ov[2], ov[3]};
        *(float4*)(o_s + h0 + 4) = (float4){ov[4], ov[5], ov[6], ov[7]};
        bf16x8 sh, sl;
#pragma unroll
        for (int r = 0; r < 8; ++r) {
          __bf16 hi = (__bf16)sv[r];
          sh[r] = hi; sl[r] = (__bf16)(sv[r] - (float)hi);
        }
        *(bf16x8*)(GtHi + 64 * 136 + h0) = sh;
        *(bf16x8*)(GtLo + 64 * 136 + h0) = sl;
      }
#pragma unroll
      for (int e = 0; e < 2; ++e) {
        int col = e0 + e;
        bf16x8 wi = *(const bf16x8*)(WtHiL + (0 * 64 + col) * 128 + h0);
        bf16x8 wf = *(const bf16x8*)(WtHiL + (1 * 64 + col) * 128 + h0);
        bf16x8 wg = *(const bf16x8*)(WtHiL + (2 * 64 + col) * 128 + h0);
        unsigned long li = *(const unsigned long*)(WtLo8L + (0 * 64 + col) * 128 + h0);
        unsigned long lf = *(const unsigned long*)(WtLo8L + (1 * 64 + col) * 128 + h0);
        unsigned long lg = *(const unsigned long*)(WtLo8L + (2 * 64 + col) * 128 + h0);
        bf16x8 gh, gl;
#pragma unroll
        for (int r = 0; r < 8; ++r) {
          float wiv = (float)wi[r] + S14 * dec8((unsigned)(li >> (8 * r)) & 0xFF);
          float wfv = (float)wf[r] + S14 * dec8((unsigned)(lf >> (8 * r)) & 0xFF);
          float wgv = (float)wg[r] + S14 * dec8((unsigned)(lg >> (8 * r)) & 0xFF);
          float gv = a1[r] * wiv + a2[r] * wfv + a3[r] * wgv;
          __bf16 hi = (__bf16)gv;
          gh[r] = hi; gl[r] = (__bf16)(gv - (float)hi);
        }
        *(bf16x8*)(GtHi + col * 136 + h0) = gh;
        *(bf16x8*)(GtLo + col * 136 + h0) = gl;
      }
    }
    __syncthreads();
    // ---- Gram via MFMA: M = I + eps*G^T G ; y = G^T s ----
    if (wv < 4) gram_do<3>(wv, 0, lane, GtHi, GtLo, M_s, y_s);
    else        gram_do<2>(wv - 4, 3, lane, GtHi, GtLo, M_s, y_s);
    __syncthreads();
    // ---- Cholesky (panel-16, readlane pivots; R4-proven) ----
#pragma unroll 1
    for (int pan = 0; pan < 4; ++pan) {
      int j0 = pan * 16;
      if (tid < 64) {
        float p[16];
#pragma unroll
        for (int jj = 0; jj < 16; ++jj) p[jj] = M_s[lane * 65 + j0 + jj];
#pragma unroll
        for (int jj = 0; jj < 16; ++jj) {
          float d  = rl(p[jj], j0 + jj);
          float rs = frsq(d);
          p[jj] *= rs;
          dinv = (lane == j0 + jj) ? rs : dinv;
#pragma unroll
          for (int kk = jj + 1; kk < 16; ++kk) {
            float l = rl(p[jj], j0 + kk);
            p[kk] -= p[jj] * l;
          }
        }
#pragma unroll
        for (int jj = 0; jj < 16; ++jj) {
          M_s[lane * 65 + j0 + jj] = p[jj];
          Lp_s[jj * 64 + lane] = p[jj];
        }
        if (pan == 3) {
          float r = y_s[lane];
#pragma unroll 16
          for (int i = 0; i < 64; ++i) {
            float Lri = M_s[lane * 65 + i];
            float vv  = rl(r, i) * rl(dinv, i);
            float upd = r - Lri * vv;
            r = (lane == i) ? vv : ((lane > i) ? upd : r);
          }
#pragma unroll 16
          for (int i = 63; i >= 0; --i) {
            float Lil = M_s[i * 65 + lane];
            float vv  = rl(r, i) * rl(dinv, i);
            float upd = r - Lil * vv;
            r = (lane == i) ? vv : ((lane < i) ? upd : r);
          }
          __bf16 xh = (__bf16)r;
          BxHi[lane] = xh;
          BxLo[lane] = (__bf16)(r - (float)xh);
        }
      }
      __syncthreads();
      if (pan < 3) {
        float Lrow[16];
#pragma unroll
        for (int jj = 0; jj < 16; ++jj) Lrow[jj] = Lp_s[jj * 64 + lane];
        for (int k = j0 + 16 + wv; k < 64; k += 8) {
          float acc = M_s[lane * 65 + k];
#pragma unroll
          for (int jj = 0; jj < 16; ++jj) acc -= Lrow[jj] * Lp_s[jj * 64 + k];
          M_s[lane * 65 + k] = acc;
        }
        __syncthreads();
      }
    }
    // ---- E: u = G x via MFMA (wave wv -> rows wv*16..); c,h update ----
    {
      bf16x8 EH[2], EL[2];
#pragma unroll
      for (int kt = 0; kt < 2; ++kt)
#pragma unroll
        for (int j = 0; j < 8; ++j) {
          int e = kt * 32 + q * 8 + j;
          EH[kt][j] = GtHi[e * 136 + wv * 16 + m];
          EL[kt][j] = GtLo[e * 136 + wv * 16 + m];
        }
      floatx4 C = {0,0,0,0};
#pragma unroll
      for (int p = 0; p < 3; ++p) {
        const __bf16* Bb = (p == 1) ? BxLo : BxHi;
#pragma unroll
        for (int kt = 0; kt < 2; ++kt) {
          bf16x8 Bf = *(const bf16x8*)(Bb + m * 72 + kt * 32 + q * 8);
          bf16x8 Af = (p < 2) ? EH[kt] : EL[kt];
          C = __builtin_amdgcn_mfma_f32_16x16x32_bf16(Af, Bf, C, 0, 0, 0);
        }
      }
      if (m == 0) {
#pragma unroll
        for (int reg = 0; reg < 4; ++reg) {
          int grow = wv * 16 + q * 4 + reg;
          float cn = s_s[grow] - EPSP * C[reg];
          float hn = o_s[grow] * ftanh(cn);
          c_s[grow] = cn;
          h_s[grow] = hn;
          __bf16 hi = (__bf16)hn;
          hbH[grow] = hi;
          hbL[grow] = (__bf16)(hn - (float)hi);
          hb8[grow] = enc8(hn * 16.f);
        }
      }
    }
    __syncthreads();
  }
  // ---- head ----
  if (tid < O_) {
    float acc = lin_b[tid];
    for (int hh2 = 0; hh2 < 128; ++hh2) acc += h_s[hh2] * lin_w[tid * 128 + hh2];
    out[(size_t)bb * O_ + tid] = acc;
  }
}

// ---------------- launch ----------------
extern "C" void kernel_launch(void* const* d_in, const int* in_sizes, int n_in,
                              void* d_out, int out_size, void* d_ws, size_t ws_size,
                              hipStream_t stream) {
  (void)in_sizes; (void)n_in; (void)out_size;
  const float* inputs  = (const float*)d_in[0];
  const float* conv_w  = (const float*)d_in[2];
  const float* conv_b  = (const float*)d_in[3];
  const float* gamma   = (const float*)d_in[4];
  const float* beta    = (const float*)d_in[5];
  const float* w_ih    = (const float*)d_in[6];
  const float* w_hh    = (const float*)d_in[7];
  const float* b_ih    = (const float*)d_in[8];
  const float* b_hh    = (const float*)d_in[9];
  const float* lin_w   = (const float*)d_in[10];
  const float* lin_b   = (const float*)d_in[11];
  float* out = (float*)d_out;
  float* ws  = (float*)d_ws;

  if (ws_size < WS_FLOATS * sizeof(float)) return;

  hipLaunchKernelGGL(prep_kernel, dim3(192), dim3(256), 0, stream, conv_w, w_ih, w_hh, ws);
  hipLaunchKernelGGL(conv_bn_kernel, dim3(1024), dim3(256), 0, stream, inputs, conv_b, ws);
  hipLaunchKernelGGL(bn_finalize_kernel, dim3(1), dim3(64), 0, stream, gamma, beta, ws);
  hipLaunchKernelGGL(zx_kernel, dim3(1024), dim3(256), 0, stream, w_ih, b_ih, b_hh, ws);
  hipLaunchKernelGGL(scan_kernel, dim3(64), dim3(512), 0, stream, lin_w, lin_b, ws, out);
}